// Round 4
// baseline (3620.140 us; speedup 1.0000x reference)
//
#include <hip/hip_runtime.h>
#include <math.h>

#define DIM 384
#define HEADS 12
#define MTOT 65536  // total tokens = 16*64*64

// ---------- LayerNorm (+ optional shifted-window gather for LN1) ----------
template<bool GATHER>
__global__ __launch_bounds__(128)
void ln_kernel(const float* __restrict__ x, const float* __restrict__ g,
               const float* __restrict__ b, float* __restrict__ y)
{
    int r = blockIdx.x;
    size_t src;
    if (GATHER) {
        int win = r >> 6, tok = r & 63;
        int wd = win >> 8, wh = (win >> 4) & 15, ww = win & 15;
        int zd = tok >> 4, zh = (tok >> 2) & 3, zw = tok & 3;
        int d = ((wd << 2) + zd + 2) & 15;
        int h = ((wh << 2) + zh + 2) & 63;
        int w = ((ww << 2) + zw + 2) & 63;
        src = (size_t)((((d << 6) + h) << 6) + w);
    } else {
        src = (size_t)r;
    }
    const float* xr = x + src * (size_t)DIM;
    int t = threadIdx.x;
    float v0 = xr[t], v1 = xr[t + 128], v2 = xr[t + 256];
    float s  = v0 + v1 + v2;
    float ss = v0 * v0 + v1 * v1 + v2 * v2;
    #pragma unroll
    for (int off = 32; off > 0; off >>= 1) {
        s  += __shfl_down(s, off);
        ss += __shfl_down(ss, off);
    }
    __shared__ float sm[4];
    if ((t & 63) == 0) { sm[t >> 6] = s; sm[2 + (t >> 6)] = ss; }
    __syncthreads();
    float S = sm[0] + sm[1], SS = sm[2] + sm[3];
    float mu  = S * (1.0f / DIM);
    float var = SS * (1.0f / DIM) - mu * mu;
    float rs  = rsqrtf(var + 1e-5f);
    float* yr = y + (size_t)r * DIM;
    yr[t]       = (v0 - mu) * rs * g[t]       + b[t];
    yr[t + 128] = (v1 - mu) * rs * g[t + 128] + b[t + 128];
    yr[t + 256] = (v2 - mu) * rs * g[t + 256] + b[t + 256];
}

// ---------- fp32 tiled GEMM: out = A(MxK) @ W(KxN) + bias, epilogues ----------
// EPI 0: +bias                          -> out[m*N+n]
// EPI 1: +bias, exact GELU              -> out[m*N+n]
// EPI 2: +bias, window-reverse+roll scatter, += res (x spatial)  (N==384)
//        NOTE: m is GLOBAL row (launch covers all MTOT rows)
// EPI 3: +bias, += res (row-aligned residual; res/out may alias per-element)
template<int EPI>
__global__ __launch_bounds__(256)
void gemm_kernel(const float* __restrict__ A, const float* __restrict__ W,
                 const float* __restrict__ bias, const float* __restrict__ res,
                 float* __restrict__ out, int M, int N, int K)
{
    __shared__ float As[16][68];  // [k][m]
    __shared__ float Bs[16][68];  // [k][n]
    int tid = threadIdx.x;
    int bm = blockIdx.y << 6;
    int bn = blockIdx.x << 6;
    int tx = tid & 15, ty = tid >> 4;
    float acc[4][4] = {};
    int ar = tid >> 2, ak = (tid & 3) << 2;   // A: 64 rows x 16 k, float4 in k
    int bk = tid >> 4, bn4 = (tid & 15) << 2; // B: 16 k x 64 n, float4 in n
    const float* Aptr = A + (size_t)(bm + ar) * K + ak;
    const float* Wptr = W + (size_t)bk * N + bn + bn4;
    for (int k0 = 0; k0 < K; k0 += 16) {
        float4 av = *(const float4*)(Aptr + k0);
        float4 bv = *(const float4*)(Wptr + (size_t)k0 * N);
        __syncthreads();
        As[ak + 0][ar] = av.x; As[ak + 1][ar] = av.y;
        As[ak + 2][ar] = av.z; As[ak + 3][ar] = av.w;
        Bs[bk][bn4 + 0] = bv.x; Bs[bk][bn4 + 1] = bv.y;
        Bs[bk][bn4 + 2] = bv.z; Bs[bk][bn4 + 3] = bv.w;
        __syncthreads();
        #pragma unroll
        for (int k = 0; k < 16; ++k) {
            float a0 = As[k][(ty << 2) + 0], a1 = As[k][(ty << 2) + 1];
            float a2 = As[k][(ty << 2) + 2], a3 = As[k][(ty << 2) + 3];
            float b0 = Bs[k][(tx << 2) + 0], b1 = Bs[k][(tx << 2) + 1];
            float b2 = Bs[k][(tx << 2) + 2], b3 = Bs[k][(tx << 2) + 3];
            acc[0][0] += a0 * b0; acc[0][1] += a0 * b1; acc[0][2] += a0 * b2; acc[0][3] += a0 * b3;
            acc[1][0] += a1 * b0; acc[1][1] += a1 * b1; acc[1][2] += a1 * b2; acc[1][3] += a1 * b3;
            acc[2][0] += a2 * b0; acc[2][1] += a2 * b1; acc[2][2] += a2 * b2; acc[2][3] += a2 * b3;
            acc[3][0] += a3 * b0; acc[3][1] += a3 * b1; acc[3][2] += a3 * b2; acc[3][3] += a3 * b3;
        }
    }
    #pragma unroll
    for (int i = 0; i < 4; ++i) {
        int m = bm + (ty << 2) + i;
        size_t orow;
        if (EPI == 2) {
            int win = m >> 6, tok = m & 63;
            int wd = win >> 8, wh = (win >> 4) & 15, ww = win & 15;
            int zd = tok >> 4, zh = (tok >> 2) & 3, zw = tok & 3;
            int d = ((wd << 2) + zd + 2) & 15;
            int h = ((wh << 2) + zh + 2) & 63;
            int w = ((ww << 2) + zw + 2) & 63;
            orow = (size_t)((((d << 6) + h) << 6) + w);
        } else {
            orow = (size_t)m;
        }
        #pragma unroll
        for (int j = 0; j < 4; ++j) {
            int n = bn + (tx << 2) + j;
            float v = acc[i][j] + bias[n];
            if (EPI == 1) v = 0.5f * v * (1.0f + erff(v * 0.70710678118654752f));
            size_t oidx = orow * (size_t)N + n;
            if (EPI == 2 || EPI == 3) v += res[oidx];
            out[oidx] = v;
        }
    }
}

// ---------- attention: one wave per (window, head); chunk-local win ----------
__global__ __launch_bounds__(64)
void attn_kernel(const float* __restrict__ qkv, const float* __restrict__ rpb,
                 float* __restrict__ o)
{
    __shared__ float Ks[64][32];
    __shared__ float Vs[64][32];
    int win = blockIdx.x, head = blockIdx.y;
    int t = threadIdx.x;
    const float scale = 0.17677669529663687f;  // 32^-0.5
    size_t base = ((size_t)(win << 6) + t) * (size_t)(3 * DIM) + head * 32;
    float q[32];
    #pragma unroll
    for (int d0 = 0; d0 < 32; d0 += 4) {
        float4 qv = *(const float4*)(qkv + base + d0);
        q[d0 + 0] = qv.x; q[d0 + 1] = qv.y; q[d0 + 2] = qv.z; q[d0 + 3] = qv.w;
        float4 kv = *(const float4*)(qkv + base + DIM + d0);
        Ks[t][d0 + 0] = kv.x; Ks[t][d0 + 1] = kv.y; Ks[t][d0 + 2] = kv.z; Ks[t][d0 + 3] = kv.w;
        float4 vv = *(const float4*)(qkv + base + 2 * DIM + d0);
        Vs[t][d0 + 0] = vv.x; Vs[t][d0 + 1] = vv.y; Vs[t][d0 + 2] = vv.z; Vs[t][d0 + 3] = vv.w;
    }
    __syncthreads();
    int zd = t >> 4, zh = (t >> 2) & 3, zw = t & 3;
    float sc[64];
    #pragma unroll
    for (int m = 0; m < 64; ++m) {
        float s = 0.0f;
        #pragma unroll
        for (int d = 0; d < 32; ++d) s += q[d] * Ks[m][d];
        int md = m >> 4, mh = (m >> 2) & 3, mw = m & 3;
        int idx = (zd - md + 3) * 49 + (zh - mh + 3) * 7 + (zw - mw + 3);
        sc[m] = s * scale + rpb[idx * HEADS + head];
    }
    float mx = sc[0];
    #pragma unroll
    for (int m = 1; m < 64; ++m) mx = fmaxf(mx, sc[m]);
    float sum = 0.0f;
    #pragma unroll
    for (int m = 0; m < 64; ++m) { sc[m] = expf(sc[m] - mx); sum += sc[m]; }
    float inv = 1.0f / sum;
    size_t ob = ((size_t)(win << 6) + t) * (size_t)DIM + head * 32;
    #pragma unroll
    for (int d0 = 0; d0 < 32; d0 += 4) {
        float a0 = 0, a1 = 0, a2 = 0, a3 = 0;
        #pragma unroll
        for (int m = 0; m < 64; ++m) {
            float p = sc[m];
            a0 += p * Vs[m][d0 + 0];
            a1 += p * Vs[m][d0 + 1];
            a2 += p * Vs[m][d0 + 2];
            a3 += p * Vs[m][d0 + 3];
        }
        o[ob + d0 + 0] = a0 * inv; o[ob + d0 + 1] = a1 * inv;
        o[ob + d0 + 2] = a2 * inv; o[ob + d0 + 3] = a3 * inv;
    }
}

extern "C" void kernel_launch(void* const* d_in, const int* in_sizes, int n_in,
                              void* d_out, int out_size, void* d_ws, size_t ws_size,
                              hipStream_t stream)
{
    const float* x      = (const float*)d_in[0];
    const float* ln1_g  = (const float*)d_in[1];
    const float* ln1_b  = (const float*)d_in[2];
    const float* qkv_w  = (const float*)d_in[3];
    const float* qkv_b  = (const float*)d_in[4];
    const float* rpb    = (const float*)d_in[5];
    const float* proj_w = (const float*)d_in[6];
    const float* proj_b = (const float*)d_in[7];
    const float* ln2_g  = (const float*)d_in[8];
    const float* ln2_b  = (const float*)d_in[9];
    const float* mlp_w1 = (const float*)d_in[10];
    const float* mlp_b1 = (const float*)d_in[11];
    const float* mlp_w2 = (const float*)d_in[12];
    const float* mlp_b2 = (const float*)d_in[13];
    float* out = (float*)d_out;

    // workspace: W1 (65536x384 fp32, 100.7 MB) + CH (row-chunk buffer for the
    // 1152/1536-wide intermediates). x2 lives in d_out. Chunk rows chosen from
    // ws_size (constant across calls -> graph-safe).
    float* W1 = (float*)d_ws;
    float* CH = W1 + (size_t)MTOT * DIM;
    size_t ws_floats = ws_size / sizeof(float);
    size_t rem = ws_floats > (size_t)MTOT * DIM ? ws_floats - (size_t)MTOT * DIM : 0;
    int rows_chunk = 1024;
    for (int rc = MTOT; rc >= 1024; rc >>= 1)
        if ((size_t)rc * 1536 <= rem) { rows_chunk = rc; break; }

    // 1. LN1 + roll + window partition: x -> W1 (y_win)
    ln_kernel<true><<<MTOT, 128, 0, stream>>>(x, ln1_g, ln1_b, W1);

    // 2+3. per row-chunk: QKV GEMM (y_win -> CH), attention (CH -> W1 o_win,
    //      overwriting this chunk's now-dead y_win rows)
    for (int r0 = 0; r0 < MTOT; r0 += rows_chunk) {
        gemm_kernel<0><<<dim3(1152 / 64, rows_chunk / 64), 256, 0, stream>>>(
            W1 + (size_t)r0 * DIM, qkv_w, qkv_b, nullptr, CH, rows_chunk, 1152, 384);
        attn_kernel<<<dim3(rows_chunk / 64, HEADS), 64, 0, stream>>>(
            CH, rpb, W1 + (size_t)r0 * DIM);
    }

    // 4. proj GEMM + window-reverse + roll + residual: W1 + x -> d_out (x2)
    gemm_kernel<2><<<dim3(384 / 64, MTOT / 64), 256, 0, stream>>>(
        W1, proj_w, proj_b, x, out, MTOT, 384, 384);

    // 5. LN2: d_out -> W1 (y2)
    ln_kernel<false><<<MTOT, 128, 0, stream>>>(out, ln2_g, ln2_b, W1);

    // 6+7. per row-chunk: MLP1+GELU (y2 -> CH), MLP2 + residual (CH + d_out -> d_out)
    for (int r0 = 0; r0 < MTOT; r0 += rows_chunk) {
        gemm_kernel<1><<<dim3(1536 / 64, rows_chunk / 64), 256, 0, stream>>>(
            W1 + (size_t)r0 * DIM, mlp_w1, mlp_b1, nullptr, CH, rows_chunk, 1536, 384);
        gemm_kernel<3><<<dim3(384 / 64, rows_chunk / 64), 256, 0, stream>>>(
            CH, mlp_w2, mlp_b2, out + (size_t)r0 * DIM, out + (size_t)r0 * DIM,
            rows_chunk, 384, 1536);
    }
}

// Round 5
// 799.309 us; speedup vs baseline: 4.5291x; 4.5291x over previous
//
#include <hip/hip_runtime.h>
#include <math.h>

#define DIM 384
#define HEADS 12
#define MTOT 65536  // total tokens = 16*64*64

typedef _Float16 f16;
typedef f16 f16x8 __attribute__((ext_vector_type(8)));
typedef float f32x4 __attribute__((ext_vector_type(4)));

typedef const __attribute__((address_space(1))) unsigned int* gas1;
typedef __attribute__((address_space(3))) unsigned int* las3;

// ---------- LayerNorm (+ optional shifted-window gather), fp16 out ----------
template<bool GATHER>
__global__ __launch_bounds__(128)
void ln_kernel(const float* __restrict__ x, const float* __restrict__ g,
               const float* __restrict__ b, f16* __restrict__ y)
{
    int r = blockIdx.x;
    size_t src;
    if (GATHER) {
        int win = r >> 6, tok = r & 63;
        int wd = win >> 8, wh = (win >> 4) & 15, ww = win & 15;
        int zd = tok >> 4, zh = (tok >> 2) & 3, zw = tok & 3;
        int d = ((wd << 2) + zd + 2) & 15;
        int h = ((wh << 2) + zh + 2) & 63;
        int w = ((ww << 2) + zw + 2) & 63;
        src = (size_t)((((d << 6) + h) << 6) + w);
    } else {
        src = (size_t)r;
    }
    const float* xr = x + src * (size_t)DIM;
    int t = threadIdx.x;
    float v0 = xr[t], v1 = xr[t + 128], v2 = xr[t + 256];
    float s  = v0 + v1 + v2;
    float ss = v0 * v0 + v1 * v1 + v2 * v2;
    #pragma unroll
    for (int off = 32; off > 0; off >>= 1) {
        s  += __shfl_down(s, off);
        ss += __shfl_down(ss, off);
    }
    __shared__ float sm[4];
    if ((t & 63) == 0) { sm[t >> 6] = s; sm[2 + (t >> 6)] = ss; }
    __syncthreads();
    float S = sm[0] + sm[1], SS = sm[2] + sm[3];
    float mu  = S * (1.0f / DIM);
    float var = SS * (1.0f / DIM) - mu * mu;
    float rs  = rsqrtf(var + 1e-5f);
    f16* yr = y + (size_t)r * DIM;
    yr[t]       = (f16)((v0 - mu) * rs * g[t]       + b[t]);
    yr[t + 128] = (f16)((v1 - mu) * rs * g[t + 128] + b[t + 128]);
    yr[t + 256] = (f16)((v2 - mu) * rs * g[t + 256] + b[t + 256]);
}

// ---------- weight convert + transpose: W[K][N] fp32 -> Wt[N][K] fp16 ----------
__global__ __launch_bounds__(128)
void wcvt_kernel(const float* __restrict__ W, f16* __restrict__ Wt, int N, int K)
{
    int k = blockIdx.x * 128 + threadIdx.x;
    int n = blockIdx.y;
    Wt[(size_t)n * K + k] = (f16)W[(size_t)k * N + n];
}

// ---------- staging helper: 128x32-half tile via global_load_lds (swizzled src) ----------
__device__ __forceinline__ void stage_pair(const f16* __restrict__ Ag, const f16* __restrict__ Bg,
                                           f16* Asb, f16* Bsb, int K, int kt, int wv, int lane)
{
    #pragma unroll
    for (int i = 0; i < 2; ++i) {
        int r  = wv * 32 + i * 16 + (lane >> 2);
        int c  = lane & 3;
        int gc = c ^ ((r >> 1) & 3);                 // inverse-swizzled global chunk
        const f16* ga = Ag + (size_t)r * K + kt * 32 + gc * 8;
        const f16* gb = Bg + (size_t)r * K + kt * 32 + gc * 8;
        __builtin_amdgcn_global_load_lds((gas1)ga, (las3)(Asb + r * 32 + c * 8), 16, 0, 0);
        __builtin_amdgcn_global_load_lds((gas1)gb, (las3)(Bsb + r * 32 + c * 8), 16, 0, 0);
    }
}

// ---------- fp16 MFMA GEMM: out = A(Mx K) @ Wt(N x K)^T + bias, epilogues ----------
// EPI 0: +bias -> f16 out[m*N+n]
// EPI 1: +bias, exact GELU -> f16 out[m*N+n]
// EPI 2: +bias, window-reverse+roll scatter, += res -> f32 out (N==384, m GLOBAL)
// EPI 3: +bias, += res (row-aligned) -> f32 out (N==384)
template<int EPI>
__global__ __launch_bounds__(256)
void gemm_kernel(const f16* __restrict__ A, const f16* __restrict__ Wt,
                 const float* __restrict__ bias, const float* __restrict__ res,
                 void* __restrict__ outv, int N, int K)
{
    __shared__ f16 As[2][128 * 32];
    __shared__ f16 Bs[2][128 * 32];
    int tid = threadIdx.x;
    int lane = tid & 63, wv = tid >> 6;
    int bm = blockIdx.y << 7, bn = blockIdx.x << 7;
    int fr = lane & 15, fq = lane >> 4;
    int wr = wv >> 1, wc = wv & 1;

    const f16* Ag = A  + (size_t)bm * K;
    const f16* Bg = Wt + (size_t)bn * K;

    f32x4 zero4 = {0.f, 0.f, 0.f, 0.f};
    f32x4 acc[4][4];
    #pragma unroll
    for (int i = 0; i < 4; ++i)
        #pragma unroll
        for (int j = 0; j < 4; ++j) acc[i][j] = zero4;

    int nk = K >> 5;
    stage_pair(Ag, Bg, As[0], Bs[0], K, 0, wv, lane);
    for (int t = 0; t < nk; ++t) {
        int cur = t & 1;
        __syncthreads();  // drains vmcnt+lgkmcnt: staged tile ready, prev reads done
        if (t + 1 < nk) stage_pair(Ag, Bg, As[cur ^ 1], Bs[cur ^ 1], K, t + 1, wv, lane);
        f16x8 a[4], b[4];
        #pragma unroll
        for (int i = 0; i < 4; ++i) {
            int R  = wr * 64 + i * 16 + fr;
            int Nn = wc * 64 + i * 16 + fr;
            a[i] = *(const f16x8*)&As[cur][R  * 32 + (fq ^ ((R  >> 1) & 3)) * 8];
            b[i] = *(const f16x8*)&Bs[cur][Nn * 32 + (fq ^ ((Nn >> 1) & 3)) * 8];
        }
        #pragma unroll
        for (int i = 0; i < 4; ++i)
            #pragma unroll
            for (int j = 0; j < 4; ++j)
                acc[i][j] = __builtin_amdgcn_mfma_f32_16x16x32_f16(a[i], b[j], acc[i][j], 0, 0, 0);
    }

    #pragma unroll
    for (int i = 0; i < 4; ++i) {
        int mrow = bm + wr * 64 + i * 16 + fq * 4;
        #pragma unroll
        for (int j = 0; j < 4; ++j) {
            int n = bn + wc * 64 + j * 16 + fr;
            float bi = bias[n];
            #pragma unroll
            for (int r = 0; r < 4; ++r) {
                int m = mrow + r;
                float v = acc[i][j][r] + bi;
                if constexpr (EPI == 0) {
                    ((f16*)outv)[(size_t)m * N + n] = (f16)v;
                } else if constexpr (EPI == 1) {
                    v = 0.5f * v * (1.0f + erff(v * 0.70710678118654752f));
                    ((f16*)outv)[(size_t)m * N + n] = (f16)v;
                } else if constexpr (EPI == 2) {
                    int win = m >> 6, tok = m & 63;
                    int wd = win >> 8, wh = (win >> 4) & 15, ww = win & 15;
                    int zd = tok >> 4, zh = (tok >> 2) & 3, zw = tok & 3;
                    int d = ((wd << 2) + zd + 2) & 15;
                    int h = ((wh << 2) + zh + 2) & 63;
                    int w = ((ww << 2) + zw + 2) & 63;
                    size_t orow = (size_t)((((d << 6) + h) << 6) + w);
                    ((float*)outv)[orow * DIM + n] = v + res[orow * DIM + n];
                } else {
                    ((float*)outv)[(size_t)m * DIM + n] = v + res[(size_t)m * DIM + n];
                }
            }
        }
    }
}

// ---------- attention: one wave per (window, head), MFMA QK^T and PV ----------
__global__ __launch_bounds__(64)
void attn_kernel(const f16* __restrict__ qkv, const float* __restrict__ rpb,
                 f16* __restrict__ o)
{
    __shared__ f16 P[64][72];   // softmax'd scores, fp16, padded (144B rows, 16B-aligned)
    __shared__ f16 Vt[32][72];  // V transposed [d][token], padded
    int win = blockIdx.x, head = blockIdx.y;
    int lane = threadIdx.x;
    int fr = lane & 15, fq = lane >> 4;
    const float scale = 0.17677669529663687f;  // 32^-0.5
    const f16* qb = qkv + (size_t)win * 64 * 1152 + head * 32;

    // Q/K fragments straight from global: row = token i*16+fr, k = fq*8..+7
    f16x8 qf[4], kf[4];
    #pragma unroll
    for (int i = 0; i < 4; ++i) {
        qf[i] = *(const f16x8*)(qb + (size_t)(i * 16 + fr) * 1152 + fq * 8);
        kf[i] = *(const f16x8*)(qb + (size_t)(i * 16 + fr) * 1152 + DIM + fq * 8);
    }
    // stage V transposed (overlaps with QK MFMAs below)
    {
        const f16* vb = qb + (size_t)lane * 1152 + 2 * DIM;
        #pragma unroll
        for (int c = 0; c < 4; ++c) {
            f16x8 vv = *(const f16x8*)(vb + c * 8);
            #pragma unroll
            for (int e = 0; e < 8; ++e) Vt[c * 8 + e][lane] = vv[e];
        }
    }

    f32x4 zero4 = {0.f, 0.f, 0.f, 0.f};
    f32x4 s[4][4];
    #pragma unroll
    for (int i = 0; i < 4; ++i)
        #pragma unroll
        for (int j = 0; j < 4; ++j) s[i][j] = zero4;
    #pragma unroll
    for (int i = 0; i < 4; ++i)
        #pragma unroll
        for (int j = 0; j < 4; ++j)
            s[i][j] = __builtin_amdgcn_mfma_f32_16x16x32_f16(qf[i], kf[j], s[i][j], 0, 0, 0);

    // scale + rel-pos bias + softmax (rows spread over 16-lane groups)
    #pragma unroll
    for (int i = 0; i < 4; ++i) {
        #pragma unroll
        for (int r = 0; r < 4; ++r) {
            int zq = i * 16 + fq * 4 + r;
            int zd = zq >> 4, zh = (zq >> 2) & 3, zw = zq & 3;
            float tv[4];
            float mx = -1e30f;
            #pragma unroll
            for (int j = 0; j < 4; ++j) {
                int m = j * 16 + fr;
                int md = m >> 4, mh = (m >> 2) & 3, mw = m & 3;
                int idx = (zd - md + 3) * 49 + (zh - mh + 3) * 7 + (zw - mw + 3);
                float v = s[i][j][r] * scale + rpb[idx * HEADS + head];
                tv[j] = v;
                mx = fmaxf(mx, v);
            }
            mx = fmaxf(mx, __shfl_xor(mx, 1));
            mx = fmaxf(mx, __shfl_xor(mx, 2));
            mx = fmaxf(mx, __shfl_xor(mx, 4));
            mx = fmaxf(mx, __shfl_xor(mx, 8));
            float sum = 0.f;
            #pragma unroll
            for (int j = 0; j < 4; ++j) { tv[j] = expf(tv[j] - mx); sum += tv[j]; }
            sum += __shfl_xor(sum, 1);
            sum += __shfl_xor(sum, 2);
            sum += __shfl_xor(sum, 4);
            sum += __shfl_xor(sum, 8);
            float is = 1.0f / sum;
            #pragma unroll
            for (int j = 0; j < 4; ++j) P[zq][j * 16 + fr] = (f16)(tv[j] * is);
        }
    }
    __syncthreads();  // P/Vt writes visible

    // PV: O = P(64x64) @ V(64x32)
    f32x4 oacc[4][2];
    #pragma unroll
    for (int i = 0; i < 4; ++i)
        #pragma unroll
        for (int jd = 0; jd < 2; ++jd) oacc[i][jd] = zero4;
    #pragma unroll
    for (int i = 0; i < 4; ++i)
        #pragma unroll
        for (int jd = 0; jd < 2; ++jd)
            #pragma unroll
            for (int ks = 0; ks < 2; ++ks) {
                f16x8 pa = *(const f16x8*)&P[i * 16 + fr][ks * 32 + fq * 8];
                f16x8 vb = *(const f16x8*)&Vt[jd * 16 + fr][ks * 32 + fq * 8];
                oacc[i][jd] = __builtin_amdgcn_mfma_f32_16x16x32_f16(pa, vb, oacc[i][jd], 0, 0, 0);
            }
    #pragma unroll
    for (int i = 0; i < 4; ++i)
        #pragma unroll
        for (int jd = 0; jd < 2; ++jd)
            #pragma unroll
            for (int r = 0; r < 4; ++r)
                o[(size_t)(win * 64 + i * 16 + fq * 4 + r) * DIM + head * 32 + jd * 16 + fr]
                    = (f16)oacc[i][jd][r];
}

extern "C" void kernel_launch(void* const* d_in, const int* in_sizes, int n_in,
                              void* d_out, int out_size, void* d_ws, size_t ws_size,
                              hipStream_t stream)
{
    const float* x      = (const float*)d_in[0];
    const float* ln1_g  = (const float*)d_in[1];
    const float* ln1_b  = (const float*)d_in[2];
    const float* qkv_w  = (const float*)d_in[3];
    const float* qkv_b  = (const float*)d_in[4];
    const float* rpb    = (const float*)d_in[5];
    const float* proj_w = (const float*)d_in[6];
    const float* proj_b = (const float*)d_in[7];
    const float* ln2_g  = (const float*)d_in[8];
    const float* ln2_b  = (const float*)d_in[9];
    const float* mlp_w1 = (const float*)d_in[10];
    const float* mlp_b1 = (const float*)d_in[11];
    const float* mlp_w2 = (const float*)d_in[12];
    const float* mlp_b2 = (const float*)d_in[13];
    float* out = (float*)d_out;

    // ws layout (halves): Wt x4 (2.65MB) | Yh 65536x384 (50MB) | CH chunk x1536
    f16* wq = (f16*)d_ws;                       // [1152][384]
    f16* wp = wq + 1152 * 384;                  // [384][384]
    f16* w1 = wp + 384 * 384;                   // [1536][384]
    f16* w2 = w1 + 1536 * 384;                  // [384][1536]
    f16* Yh = w2 + 384 * 1536;
    f16* CH = Yh + (size_t)MTOT * DIM;
    size_t used_halves = (size_t)1769472 + (size_t)MTOT * DIM;
    size_t ws_halves = ws_size / 2;
    size_t remh = ws_halves > used_halves ? ws_halves - used_halves : 0;
    int rows_chunk = 1024;
    for (int rc = MTOT; rc >= 1024; rc >>= 1)
        if ((size_t)rc * 1536 <= remh) { rows_chunk = rc; break; }

    // 0. weight convert+transpose (fp32 [K][N] -> fp16 [N][K])
    wcvt_kernel<<<dim3(3, 1152), 128, 0, stream>>>(qkv_w, wq, 1152, 384);
    wcvt_kernel<<<dim3(3, 384),  128, 0, stream>>>(proj_w, wp, 384, 384);
    wcvt_kernel<<<dim3(3, 1536), 128, 0, stream>>>(mlp_w1, w1, 1536, 384);
    wcvt_kernel<<<dim3(12, 384), 128, 0, stream>>>(mlp_w2, w2, 384, 1536);

    // 1. LN1 + roll + window partition -> Yh (fp16)
    ln_kernel<true><<<MTOT, 128, 0, stream>>>(x, ln1_g, ln1_b, Yh);

    // 2+3. per chunk: QKV GEMM -> CH ; attention CH -> Yh (o_win overwrites y_win)
    for (int r0 = 0; r0 < MTOT; r0 += rows_chunk) {
        gemm_kernel<0><<<dim3(9, rows_chunk / 128), 256, 0, stream>>>(
            Yh + (size_t)r0 * DIM, wq, qkv_b, nullptr, CH, 1152, 384);
        attn_kernel<<<dim3(rows_chunk / 64, HEADS), 64, 0, stream>>>(
            CH, rpb, Yh + (size_t)r0 * DIM);
    }

    // 4. proj GEMM + window-reverse+roll + residual -> d_out (fp32), m GLOBAL
    gemm_kernel<2><<<dim3(3, MTOT / 128), 256, 0, stream>>>(
        Yh, wp, proj_b, x, out, 384, 384);

    // 5. LN2: d_out -> Yh (fp16)
    ln_kernel<false><<<MTOT, 128, 0, stream>>>(out, ln2_g, ln2_b, Yh);

    // 6+7. per chunk: MLP1+GELU -> CH ; MLP2 + residual -> d_out
    for (int r0 = 0; r0 < MTOT; r0 += rows_chunk) {
        gemm_kernel<1><<<dim3(12, rows_chunk / 128), 256, 0, stream>>>(
            Yh + (size_t)r0 * DIM, w1, mlp_b1, nullptr, CH, 1536, 384);
        gemm_kernel<3><<<dim3(3, rows_chunk / 128), 256, 0, stream>>>(
            CH, w2, mlp_b2, out + (size_t)r0 * DIM, out + (size_t)r0 * DIM, 384, 1536);
    }
}